// Round 10
// baseline (225.642 us; speedup 1.0000x reference)
//
#include <hip/hip_runtime.h>
#include <hip/hip_bf16.h>

#define TEXT_N 226
#define D_N    1024
#define HEADS_N 16
#define HD_N   64
#define ST_N   1248
#define S_N    1474        // TEXT+ST
#define L0_N   2722        // S+ST (cond key length)
#define NT_C   43          // cond j-tiles (64 each) -> 2752
#define NT_U   24          // uncond j-tiles        -> 1536
#define BC_N   (NT_C*64)   // 2752 cond bias entries
#define SP_N   1536        // padded per-batch rows
#define MB_N   24          // 128-row image blocks (3072 rows)
#define KB_N   16          // k-blocks of 64 (K=1024)
#define NEGB2  (-1.442695e9f)            // -1e9 * log2(e)
#define SCALE2 (0.125f * 1.44269504f)    // (1/sqrt(64)) * log2(e)

typedef __hip_bfloat16 bf16_t;
typedef short s16x8 __attribute__((ext_vector_type(8)));   // 8 bf16 (4 VGPRs)
typedef short s16x4 __attribute__((ext_vector_type(4)));   // 4 bf16
typedef float f32x4 __attribute__((ext_vector_type(4)));

__device__ __forceinline__ f32x4 mfma16(s16x8 a, s16x8 b, f32x4 c) {
    return __builtin_amdgcn_mfma_f32_16x16x32_bf16(a, b, c, 0, 0, 0);
}

typedef __attribute__((address_space(1))) const unsigned int gu32;
typedef __attribute__((address_space(3))) unsigned int lu32;
__device__ __forceinline__ void glds16(const void* g, void* l) {
    __builtin_amdgcn_global_load_lds((gu32*)g, (lu32*)l, 16, 0, 0);
}

// finite-only RNE f32->bf16 (matches __float2bfloat16 for finite values)
__device__ __forceinline__ short f2bs(float x) {
    unsigned u = __float_as_uint(x);
    u += 0x7FFF + ((u >> 16) & 1);
    return (short)(u >> 16);
}
// packed RNE pair -> 32-bit (v_cvt_pk_bf16_f32)
__device__ __forceinline__ unsigned pk2(float a, float b) {
    float2 f; f.x = a; f.y = b;
    __hip_bfloat162 h = __float22bfloat162_rn(f);
    return *(unsigned*)&h;
}
// swizzled elem offset inside a [R][64] bf16 tile: 16B unit XORed by (row&7)
__device__ __forceinline__ int swz(int r, int c) {
    return r * 64 + ((((c >> 3) ^ (r & 7)) << 3) | (c & 7));
}

// ---------------- prep: weight images, x image, bias vectors ----------------
__global__ __launch_bounds__(256) void prep(
    const float* __restrict__ hid, const float* __restrict__ enc,
    const int* __restrict__ mask,
    const float* __restrict__ wq, const float* __restrict__ wk,
    const float* __restrict__ wv, const float* __restrict__ wo,
    bf16_t* __restrict__ wimg, bf16_t* __restrict__ xb,
    float* __restrict__ biasc, float* __restrict__ biasu) {
    __shared__ float Lw[64 * 129];
    const int b = blockIdx.x, t = threadIdx.x;
    if (b < 512) {                       // 4 weights x 8 nblk x 16 kb
        const int wid = b >> 7, nblk = (b >> 4) & 7, kb = b & 15;
        const float* w = (wid == 0) ? wq : (wid == 1) ? wk : (wid == 2) ? wv : wo;
        const int k0 = kb * 64, n0 = nblk * 128;
#pragma unroll
        for (int i = 0; i < 8; i++) {
            int idx = t + i * 256;
            int kr = idx >> 5, c4 = (idx & 31) * 4;
            float4 v = *(const float4*)(w + (size_t)(k0 + kr) * D_N + n0 + c4);
            Lw[kr * 129 + c4 + 0] = v.x; Lw[kr * 129 + c4 + 1] = v.y;
            Lw[kr * 129 + c4 + 2] = v.z; Lw[kr * 129 + c4 + 3] = v.w;
        }
        __syncthreads();
        bf16_t* dst = wimg + (((size_t)wid * 8 + nblk) * 16 + kb) * 8192;
#pragma unroll
        for (int i = 0; i < 4; i++) {
            int u = t + i * 256;
            int r = u >> 3, p = u & 7;
            int ul = p ^ (r & 7);
            s16x8 o;
#pragma unroll
            for (int e = 0; e < 8; e++)
                o[e] = f2bs(Lw[(ul * 8 + e) * 129 + r]);
            *(s16x8*)(dst + r * 64 + p * 8) = o;
        }
    } else if (b < 896) {                // 384 x-tiles
        const int tile = b - 512;
        const int mblk = tile >> 4, kb = tile & 15;
        bf16_t* dst = xb + (size_t)tile * 8192;
#pragma unroll
        for (int i = 0; i < 4; i++) {
            int u = t + i * 256;
            int r = u >> 3, p = u & 7;
            int m = mblk * 128 + r;
            int bb = m >= SP_N; int s = m - bb * SP_N;
            if (s >= S_N) continue;
            const float* src = (s < TEXT_N)
                ? (enc + (size_t)(bb * TEXT_N + s) * D_N)
                : (hid + (size_t)(bb * ST_N + (s - TEXT_N)) * D_N);
            int k = kb * 64 + (p ^ (r & 7)) * 8;
            float4 f0 = *(const float4*)(src + k);
            float4 f1 = *(const float4*)(src + k + 4);
            s16x8 o;
            o[0]=f2bs(f0.x); o[1]=f2bs(f0.y); o[2]=f2bs(f0.z); o[3]=f2bs(f0.w);
            o[4]=f2bs(f1.x); o[5]=f2bs(f1.y); o[6]=f2bs(f1.z); o[7]=f2bs(f1.w);
            *(s16x8*)(dst + r * 64 + p * 8) = o;
        }
    } else {                             // bias vectors (exp2 domain, -8 max-shift folded in)
        int j = (b - 896) * 256 + t;
        if (j < BC_N) {
            float v = -8.f;
            if (j >= L0_N) v = NEGB2;
            else if (j >= S_N) v = (mask[j - S_N] > 0) ? -8.f : NEGB2;
            biasc[j] = v;
        }
        int j2 = j - BC_N;
        if (j2 >= 0 && j2 < SP_N) biasu[j2] = (j2 < S_N) ? -8.f : NEGB2;
    }
}

// ---------------- fused QKV projection GEMM (64M x 128N, glds dbuf) ----------------
__global__ __launch_bounds__(256) void qkv_proj(
    const bf16_t* __restrict__ xb, const bf16_t* __restrict__ wimg,
    const float* __restrict__ bq, const float* __restrict__ bk, const float* __restrict__ bv,
    bf16_t* __restrict__ Q, bf16_t* __restrict__ Kc, bf16_t* __restrict__ Ku,
    bf16_t* __restrict__ Vc, bf16_t* __restrict__ Vu) {
    __shared__ __align__(16) bf16_t As[2][4096];    // 64 x 64 dbuf
    __shared__ __align__(16) bf16_t Bs[2][8192];    // 128 x 64 dbuf
    const int z = blockIdx.z;
    const float* bias = (z == 0) ? bq : (z == 1) ? bk : bv;
    const int nblk = blockIdx.x, mblk = blockIdx.y;
    const int m0 = mblk * 64;
    const int mt = mblk >> 1, rowOff = (mblk & 1) * 64;
    const int t = threadIdx.x, wave = t >> 6, lane = t & 63, ln = lane & 15, qd = lane >> 4;
    const bf16_t* Ai = xb + ((size_t)mt * KB_N) * 8192 + rowOff * 64;
    const bf16_t* Bi = wimg + ((size_t)z * 8 + nblk) * KB_N * 8192;

    f32x4 acc[8];
    const f32x4 z4 = {0.f, 0.f, 0.f, 0.f};
#pragma unroll
    for (int ni = 0; ni < 8; ni++) acc[ni] = z4;

    // prologue: stage kb=0 into buf 0
#pragma unroll
    for (int i = 0; i < 2; i++)
        glds16(Ai + (t + i * 256) * 8, &As[0][(t + i * 256) * 8]);
#pragma unroll
    for (int i = 0; i < 4; i++)
        glds16(Bi + (t + i * 256) * 8, &Bs[0][(t + i * 256) * 8]);

    for (int kb = 0; kb < KB_N; kb++) {
        const int buf = kb & 1;
        __syncthreads();                 // drains prefetch from last iter
        if (kb + 1 < KB_N) {
            const bf16_t* at = Ai + (size_t)(kb + 1) * 8192;
            const bf16_t* bt = Bi + (size_t)(kb + 1) * 8192;
#pragma unroll
            for (int i = 0; i < 2; i++)
                glds16(at + (t + i * 256) * 8, &As[buf ^ 1][(t + i * 256) * 8]);
#pragma unroll
            for (int i = 0; i < 4; i++)
                glds16(bt + (t + i * 256) * 8, &Bs[buf ^ 1][(t + i * 256) * 8]);
        }
#pragma unroll
        for (int kk = 0; kk < 2; kk++) {
            const int po = (((kk * 4 + qd) ^ (ln & 7)) << 3);
            s16x8 af = *(const s16x8*)(&As[buf][(wave * 16 + ln) * 64 + po]);
#pragma unroll
            for (int ni = 0; ni < 8; ni++) {
                s16x8 bfr = *(const s16x8*)(&Bs[buf][(ni * 16 + ln) * 64 + po]);
                acc[ni] = mfma16(af, bfr, acc[ni]);
            }
        }
    }

    // epilogue: scatter into attention layouts
    const int b = m0 >= SP_N;            // batch uniform per block
    const int sbase = m0 - b * SP_N + wave * 16 + qd * 4;
#pragma unroll
    for (int ni = 0; ni < 8; ni++) {
        int n = nblk * 128 + ni * 16 + ln;
        float bn = bias[n];
        int h = n >> 6, d = n & 63;
        int s = sbase;
        if (s >= S_N) continue;
        if (z == 2) {
            s16x4 pk;
#pragma unroll
            for (int r = 0; r < 4; r++) pk[r] = f2bs(acc[ni][r] + bn);
            bool full = (s + 3 < S_N);
            if (!b) {
                if (full) {
                    *(s16x4*)(Vc + ((size_t)h * NT_C + (s >> 6)) * 4096 + swz(d, s & 63)) = pk;
                } else {
                    for (int r = 0; r < 4; r++)
                        if (s + r < S_N)
                            *(short*)&Vc[((size_t)h * NT_C + ((s + r) >> 6)) * 4096 + swz(d, (s + r) & 63)] = pk[r];
                }
            } else {
                if (full) {
                    *(s16x4*)(Vu + ((size_t)h * NT_U + (s >> 6)) * 4096 + swz(d, s & 63)) = pk;
                    if (s >= TEXT_N) {
                        int j = s + 1248;
                        *(s16x4*)(Vc + ((size_t)h * NT_C + (j >> 6)) * 4096 + swz(d, j & 63)) = pk;
                    } else if (s + 3 >= TEXT_N) {
                        for (int r = 0; r < 4; r++)
                            if (s + r >= TEXT_N) {
                                int j = s + r + 1248;
                                *(short*)&Vc[((size_t)h * NT_C + (j >> 6)) * 4096 + swz(d, j & 63)] = pk[r];
                            }
                    }
                } else {
                    for (int r = 0; r < 4; r++)
                        if (s + r < S_N) {
                            *(short*)&Vu[((size_t)h * NT_U + ((s + r) >> 6)) * 4096 + swz(d, (s + r) & 63)] = pk[r];
                            if (s + r >= TEXT_N) {
                                int j = s + r + 1248;
                                *(short*)&Vc[((size_t)h * NT_C + (j >> 6)) * 4096 + swz(d, j & 63)] = pk[r];
                            }
                        }
                }
            }
        } else {
#pragma unroll
            for (int r = 0; r < 4; r++) {
                int sr = s + r;
                if (sr >= S_N) continue;
                short v = f2bs(acc[ni][r] + bn);
                if (z == 0) {
                    *(short*)&Q[((size_t)(b * HEADS_N + h) * SP_N + sr) * HD_N + d] = v;
                } else {
                    if (!b) {
                        *(short*)&Kc[((size_t)h * NT_C + (sr >> 6)) * 4096 + swz(sr & 63, d)] = v;
                    } else {
                        *(short*)&Ku[((size_t)h * NT_U + (sr >> 6)) * 4096 + swz(sr & 63, d)] = v;
                        if (sr >= TEXT_N) {
                            int j = sr + 1248;
                            *(short*)&Kc[((size_t)h * NT_C + (j >> 6)) * 4096 + swz(j & 63, d)] = v;
                        }
                    }
                }
            }
        }
    }
}

// ---------------- flash attention, S^T formulation, glds double-buffer ----------------
__global__ __launch_bounds__(256) void attn_k(
    const bf16_t* __restrict__ Q, const bf16_t* __restrict__ Kc, const bf16_t* __restrict__ Ku,
    const bf16_t* __restrict__ Vc, const bf16_t* __restrict__ Vu,
    const float* __restrict__ biasc, const float* __restrict__ biasu,
    bf16_t* __restrict__ hs) {
    __shared__ __align__(16) bf16_t Ks[2][4096];   // [j][d] swizzled, dbuf
    __shared__ __align__(16) bf16_t Vs[2][4096];   // [d][j] swizzled, dbuf
    __shared__ __align__(16) bf16_t Ps[4][1024];   // per-wave P [q][j] swizzled
    __shared__ __align__(16) float  bsL[BC_N];
    const int cs = blockIdx.z, h = blockIdx.y, q0 = blockIdx.x * 64;
    const int nt = cs ? NT_U : NT_C;
    const bf16_t* Ki = cs ? (Ku + (size_t)h * NT_U * 4096) : (Kc + (size_t)h * NT_C * 4096);
    const bf16_t* Vi = cs ? (Vu + (size_t)h * NT_U * 4096) : (Vc + (size_t)h * NT_C * 4096);
    const float* bsrc = cs ? biasu : biasc;
    const int t = threadIdx.x, wave = t >> 6, lane = t & 63, ln = lane & 15, qd = lane >> 4;
    const int q = q0 + wave * 16 + ln;

    for (int i = t * 4; i < nt * 64; i += 1024)
        *(float4*)(bsL + i) = *(const float4*)(bsrc + i);

    const bf16_t* Qp = Q + ((size_t)(cs * HEADS_N + h) * SP_N + q) * HD_N;
    s16x8 qf[2];
    qf[0] = *(const s16x8*)(Qp + qd * 8);
    qf[1] = *(const s16x8*)(Qp + 32 + qd * 8);

    f32x4 o[4];
    const f32x4 z4 = {0.f, 0.f, 0.f, 0.f};
#pragma unroll
    for (int mi = 0; mi < 4; mi++) o[mi] = z4;
    f32x4 l4 = z4;                                 // vector l accumulator (deferred reduce)
    bf16_t* pw = (bf16_t*)Ps[wave];

    // prologue: stage tile 0 -> buf 0
#pragma unroll
    for (int i = 0; i < 2; i++) {
        glds16(Ki + (t + i * 256) * 8, &Ks[0][(t + i * 256) * 8]);
        glds16(Vi + (t + i * 256) * 8, &Vs[0][(t + i * 256) * 8]);
    }

    for (int kt = 0; kt < nt; kt++) {
        const int buf = kt & 1;
        __syncthreads();                               // drains prefetch from last iter
        if (kt + 1 < nt) {                             // prefetch next tile (contiguous)
            const bf16_t* kp = Ki + (size_t)(kt + 1) * 4096;
            const bf16_t* vp = Vi + (size_t)(kt + 1) * 4096;
#pragma unroll
            for (int i = 0; i < 2; i++) {
                glds16(kp + (t + i * 256) * 8, &Ks[buf ^ 1][(t + i * 256) * 8]);
                glds16(vp + (t + i * 256) * 8, &Vs[buf ^ 1][(t + i * 256) * 8]);
            }
        }

        // S^T[j][q] = sum_d K[j][d] Q[q][d]
        f32x4 st[4];
#pragma unroll
        for (int ni = 0; ni < 4; ni++) st[ni] = z4;
#pragma unroll
        for (int kk = 0; kk < 2; kk++) {
            const int po = (((kk * 4 + qd) ^ (ln & 7)) << 3);
#pragma unroll
            for (int ni = 0; ni < 4; ni++) {
                s16x8 kf = *(const s16x8*)(&Ks[buf][(ni * 16 + ln) * 64 + po]);
                st[ni] = mfma16(kf, qf[kk], st[ni]);
            }
        }
        // p = exp2(s*SCALE2 + bias-8); vector ops -> v_pk_fma/pk_add
#pragma unroll
        for (int ni = 0; ni < 4; ni++) {
            f32x4 bv4 = *(const f32x4*)(bsL + kt * 64 + ni * 16 + qd * 4);
            f32x4 s = st[ni] * SCALE2 + bv4;
            f32x4 p;
            p[0] = exp2f(s[0]); p[1] = exp2f(s[1]);
            p[2] = exp2f(s[2]); p[3] = exp2f(s[3]);
            st[ni] = p;
            l4 += p;
        }
        // pack P -> per-wave LDS (8B, swizzled)
#pragma unroll
        for (int ni = 0; ni < 4; ni++) {
            uint2 pk;
            pk.x = pk2(st[ni][0], st[ni][1]);
            pk.y = pk2(st[ni][2], st[ni][3]);
            int c0 = ni * 16 + qd * 4;
            *(uint2*)&pw[ln * 64 + ((((c0 >> 3) ^ (ln & 7)) << 3) | (c0 & 7))] = pk;
        }
        asm volatile("s_waitcnt lgkmcnt(0)" ::: "memory");  // DS-only: keeps prefetch in flight
        // O^T[d][q] += V^T P
#pragma unroll
        for (int kk = 0; kk < 2; kk++) {
            const int po = (((kk * 4 + qd) ^ (ln & 7)) << 3);
            s16x8 pb = *(const s16x8*)(&pw[ln * 64 + po]);
#pragma unroll
            for (int mi = 0; mi < 4; mi++) {
                s16x8 vf = *(const s16x8*)(&Vs[buf][(mi * 16 + ln) * 64 + po]);
                o[mi] = mfma16(vf, pb, o[mi]);
            }
        }
    }
    // deferred l reduction (pure sum, associative)
    float l_r = (l4[0] + l4[1]) + (l4[2] + l4[3]);
    l_r += __shfl_xor(l_r, 16);
    l_r += __shfl_xor(l_r, 32);
    if (q < S_N) {
        float inv = 1.f / l_r;
        int m = cs * SP_N + q;
        bf16_t* dst = hs + ((size_t)(m >> 7) * 16 + h) * 8192;
        int r = m & 127;
#pragma unroll
        for (int mi = 0; mi < 4; mi++) {
            uint2 ov;
            ov.x = pk2(o[mi][0] * inv, o[mi][1] * inv);
            ov.y = pk2(o[mi][2] * inv, o[mi][3] * inv);
            int c0 = mi * 16 + qd * 4;
            *(uint2*)&dst[r * 64 + ((((c0 >> 3) ^ (r & 7)) << 3) | (c0 & 7))] = ov;
        }
    }
}

// ---------------- output projection GEMM (64M x 128N, glds dbuf) + split fp32 store ----------------
__global__ __launch_bounds__(256) void out_proj(
    const bf16_t* __restrict__ hsi, const bf16_t* __restrict__ wimg,
    const float* __restrict__ bo, float* __restrict__ out) {
    __shared__ __align__(16) bf16_t As[2][4096];    // 64 x 64 dbuf
    __shared__ __align__(16) bf16_t Bs[2][8192];    // 128 x 64 dbuf
    const int nblk = blockIdx.x, mblk = blockIdx.y;
    const int m0 = mblk * 64;
    const int mt = mblk >> 1, rowOff = (mblk & 1) * 64;
    const int t = threadIdx.x, wave = t >> 6, lane = t & 63, ln = lane & 15, qd = lane >> 4;
    const bf16_t* Ai = hsi + ((size_t)mt * KB_N) * 8192 + rowOff * 64;
    const bf16_t* Bi = wimg + ((size_t)3 * 8 + nblk) * KB_N * 8192;

    f32x4 acc[8];
    const f32x4 z4 = {0.f, 0.f, 0.f, 0.f};
#pragma unroll
    for (int ni = 0; ni < 8; ni++) acc[ni] = z4;

    // prologue: stage kb=0 into buf 0
#pragma unroll
    for (int i = 0; i < 2; i++)
        glds16(Ai + (t + i * 256) * 8, &As[0][(t + i * 256) * 8]);
#pragma unroll
    for (int i = 0; i < 4; i++)
        glds16(Bi + (t + i * 256) * 8, &Bs[0][(t + i * 256) * 8]);

    for (int kb = 0; kb < KB_N; kb++) {
        const int buf = kb & 1;
        __syncthreads();
        if (kb + 1 < KB_N) {
            const bf16_t* at = Ai + (size_t)(kb + 1) * 8192;
            const bf16_t* bt = Bi + (size_t)(kb + 1) * 8192;
#pragma unroll
            for (int i = 0; i < 2; i++)
                glds16(at + (t + i * 256) * 8, &As[buf ^ 1][(t + i * 256) * 8]);
#pragma unroll
            for (int i = 0; i < 4; i++)
                glds16(bt + (t + i * 256) * 8, &Bs[buf ^ 1][(t + i * 256) * 8]);
        }
#pragma unroll
        for (int kk = 0; kk < 2; kk++) {
            const int po = (((kk * 4 + qd) ^ (ln & 7)) << 3);
            s16x8 af = *(const s16x8*)(&As[buf][(wave * 16 + ln) * 64 + po]);
#pragma unroll
            for (int ni = 0; ni < 8; ni++) {
                s16x8 bfr = *(const s16x8*)(&Bs[buf][(ni * 16 + ln) * 64 + po]);
                acc[ni] = mfma16(af, bfr, acc[ni]);
            }
        }
    }
    const int b = m0 >= SP_N;
    const int sbase = m0 - b * SP_N + wave * 16 + qd * 4;
#pragma unroll
    for (int ni = 0; ni < 8; ni++) {
        int n = nblk * 128 + ni * 16 + ln;
        float bn = bo[n];
#pragma unroll
        for (int r = 0; r < 4; r++) {
            int s = sbase + r;
            if (s >= S_N) continue;
            float v = acc[ni][r] + bn;
            size_t off = (s >= TEXT_N)
                ? ((size_t)(b * ST_N + (s - TEXT_N)) * D_N + n)
                : ((size_t)2 * ST_N * D_N + (size_t)(b * TEXT_N + s) * D_N + n);
            out[off] = v;
        }
    }
}

extern "C" void kernel_launch(void* const* d_in, const int* in_sizes, int n_in,
                              void* d_out, int out_size, void* d_ws, size_t ws_size,
                              hipStream_t stream) {
    const float* hid = (const float*)d_in[0];
    const float* enc = (const float*)d_in[1];
    const int*  mask = (const int*)d_in[2];
    const float* wq = (const float*)d_in[3];
    const float* bq = (const float*)d_in[4];
    const float* wk = (const float*)d_in[5];
    const float* bk = (const float*)d_in[6];
    const float* wv = (const float*)d_in[7];
    const float* bv = (const float*)d_in[8];
    const float* wo = (const float*)d_in[9];
    const float* bo = (const float*)d_in[10];

    bf16_t* w = (bf16_t*)d_ws;
    const size_t WIMG = (size_t)4 * 8 * 16 * 8192;        // 4,194,304
    const size_t XIMG = (size_t)MB_N * KB_N * 8192;       // 3,145,728
    bf16_t* wimg = w;
    bf16_t* xb   = wimg + WIMG;
    bf16_t* Qb   = xb + XIMG;                             // [2][16][1536][64]
    bf16_t* Kc   = Qb + (size_t)2 * HEADS_N * SP_N * HD_N;// [16][43][4096]
    bf16_t* Ku   = Kc + (size_t)HEADS_N * NT_C * 4096;    // [16][24][4096]
    bf16_t* Vc   = Ku + (size_t)HEADS_N * NT_U * 4096;    // [16][43][4096]
    bf16_t* Vu   = Vc + (size_t)HEADS_N * NT_C * 4096;    // [16][24][4096]
    float*  biasc = (float*)(Vu + (size_t)HEADS_N * NT_U * 4096);
    float*  biasu = biasc + BC_N;
    bf16_t* hsi  = xb;   // reuse x-image region for hs image (xb dead after qkv_proj)

    prep<<<913, 256, 0, stream>>>(hid, enc, mask, wq, wk, wv, wo, wimg, xb, biasc, biasu);
    qkv_proj<<<dim3(8, 48, 3), 256, 0, stream>>>(xb, wimg, bq, bk, bv, Qb, Kc, Ku, Vc, Vu);
    attn_k<<<dim3(24, 16, 2), 256, 0, stream>>>(Qb, Kc, Ku, Vc, Vu, biasc, biasu, hsi);
    out_proj<<<dim3(8, 48), 256, 0, stream>>>(hsi, wimg, bo, (float*)d_out);
}

// Round 11
// 202.929 us; speedup vs baseline: 1.1119x; 1.1119x over previous
//
#include <hip/hip_runtime.h>
#include <hip/hip_bf16.h>

#define TEXT_N 226
#define D_N    1024
#define HEADS_N 16
#define HD_N   64
#define ST_N   1248
#define S_N    1474        // TEXT+ST
#define L0_N   2722        // S+ST (cond key length)
#define NT_C   43          // cond j-tiles (64 each) -> 2752
#define NT_U   24          // uncond j-tiles        -> 1536
#define BC_N   (NT_C*64)   // 2752 cond bias entries
#define SP_N   1536        // padded per-batch rows
#define MB_N   24          // 128-row image blocks (3072 rows)
#define KB_N   16          // k-blocks of 64 (K=1024)
#define NEGB2  (-1.442695e9f)            // -1e9 * log2(e)
#define SCALE2 (0.125f * 1.44269504f)    // (1/sqrt(64)) * log2(e)

typedef __hip_bfloat16 bf16_t;
typedef short s16x8 __attribute__((ext_vector_type(8)));   // 8 bf16 (4 VGPRs)
typedef short s16x4 __attribute__((ext_vector_type(4)));   // 4 bf16
typedef float f32x4 __attribute__((ext_vector_type(4)));

__device__ __forceinline__ f32x4 mfma16(s16x8 a, s16x8 b, f32x4 c) {
    return __builtin_amdgcn_mfma_f32_16x16x32_bf16(a, b, c, 0, 0, 0);
}

typedef __attribute__((address_space(1))) const unsigned int gu32;
typedef __attribute__((address_space(3))) unsigned int lu32;
__device__ __forceinline__ void glds16(const void* g, void* l) {
    __builtin_amdgcn_global_load_lds((gu32*)g, (lu32*)l, 16, 0, 0);
}

// finite-only RNE f32->bf16 (matches __float2bfloat16 for finite values)
__device__ __forceinline__ short f2bs(float x) {
    unsigned u = __float_as_uint(x);
    u += 0x7FFF + ((u >> 16) & 1);
    return (short)(u >> 16);
}
// packed RNE pair -> 32-bit (v_cvt_pk_bf16_f32)
__device__ __forceinline__ unsigned pk2(float a, float b) {
    float2 f; f.x = a; f.y = b;
    __hip_bfloat162 h = __float22bfloat162_rn(f);
    return *(unsigned*)&h;
}
// swizzled elem offset inside a [R][64] bf16 tile: 16B unit XORed by (row&7)
__device__ __forceinline__ int swz(int r, int c) {
    return r * 64 + ((((c >> 3) ^ (r & 7)) << 3) | (c & 7));
}

// ---------------- prep: weight images, x image, bias vectors ----------------
__global__ __launch_bounds__(256) void prep(
    const float* __restrict__ hid, const float* __restrict__ enc,
    const int* __restrict__ mask,
    const float* __restrict__ wq, const float* __restrict__ wk,
    const float* __restrict__ wv, const float* __restrict__ wo,
    bf16_t* __restrict__ wimg, bf16_t* __restrict__ xb,
    float* __restrict__ biasc, float* __restrict__ biasu) {
    __shared__ float Lw[64 * 129];
    const int b = blockIdx.x, t = threadIdx.x;
    if (b < 512) {                       // 4 weights x 8 nblk x 16 kb
        const int wid = b >> 7, nblk = (b >> 4) & 7, kb = b & 15;
        const float* w = (wid == 0) ? wq : (wid == 1) ? wk : (wid == 2) ? wv : wo;
        const int k0 = kb * 64, n0 = nblk * 128;
#pragma unroll
        for (int i = 0; i < 8; i++) {
            int idx = t + i * 256;
            int kr = idx >> 5, c4 = (idx & 31) * 4;
            float4 v = *(const float4*)(w + (size_t)(k0 + kr) * D_N + n0 + c4);
            Lw[kr * 129 + c4 + 0] = v.x; Lw[kr * 129 + c4 + 1] = v.y;
            Lw[kr * 129 + c4 + 2] = v.z; Lw[kr * 129 + c4 + 3] = v.w;
        }
        __syncthreads();
        bf16_t* dst = wimg + (((size_t)wid * 8 + nblk) * 16 + kb) * 8192;
#pragma unroll
        for (int i = 0; i < 4; i++) {
            int u = t + i * 256;
            int r = u >> 3, p = u & 7;
            int ul = p ^ (r & 7);
            s16x8 o;
#pragma unroll
            for (int e = 0; e < 8; e++)
                o[e] = f2bs(Lw[(ul * 8 + e) * 129 + r]);
            *(s16x8*)(dst + r * 64 + p * 8) = o;
        }
    } else if (b < 896) {                // 384 x-tiles
        const int tile = b - 512;
        const int mblk = tile >> 4, kb = tile & 15;
        bf16_t* dst = xb + (size_t)tile * 8192;
#pragma unroll
        for (int i = 0; i < 4; i++) {
            int u = t + i * 256;
            int r = u >> 3, p = u & 7;
            int m = mblk * 128 + r;
            int bb = m >= SP_N; int s = m - bb * SP_N;
            if (s >= S_N) continue;
            const float* src = (s < TEXT_N)
                ? (enc + (size_t)(bb * TEXT_N + s) * D_N)
                : (hid + (size_t)(bb * ST_N + (s - TEXT_N)) * D_N);
            int k = kb * 64 + (p ^ (r & 7)) * 8;
            float4 f0 = *(const float4*)(src + k);
            float4 f1 = *(const float4*)(src + k + 4);
            s16x8 o;
            o[0]=f2bs(f0.x); o[1]=f2bs(f0.y); o[2]=f2bs(f0.z); o[3]=f2bs(f0.w);
            o[4]=f2bs(f1.x); o[5]=f2bs(f1.y); o[6]=f2bs(f1.z); o[7]=f2bs(f1.w);
            *(s16x8*)(dst + r * 64 + p * 8) = o;
        }
    } else {                             // bias vectors (exp2 domain, -8 max-shift folded in)
        int j = (b - 896) * 256 + t;
        if (j < BC_N) {
            float v = -8.f;
            if (j >= L0_N) v = NEGB2;
            else if (j >= S_N) v = (mask[j - S_N] > 0) ? -8.f : NEGB2;
            biasc[j] = v;
        }
        int j2 = j - BC_N;
        if (j2 >= 0 && j2 < SP_N) biasu[j2] = (j2 < S_N) ? -8.f : NEGB2;
    }
}

// ---------------- fused QKV projection GEMM (64M x 128N, glds staging) ----------------
__global__ __launch_bounds__(256) void qkv_proj(
    const bf16_t* __restrict__ xb, const bf16_t* __restrict__ wimg,
    const float* __restrict__ bq, const float* __restrict__ bk, const float* __restrict__ bv,
    bf16_t* __restrict__ Q, bf16_t* __restrict__ Kc, bf16_t* __restrict__ Ku,
    bf16_t* __restrict__ Vc, bf16_t* __restrict__ Vu) {
    __shared__ __align__(16) bf16_t As[4096];    // 64 x 64
    __shared__ __align__(16) bf16_t Bs[8192];    // 128 x 64
    const int z = blockIdx.z;
    const float* bias = (z == 0) ? bq : (z == 1) ? bk : bv;
    const int nblk = blockIdx.x, mblk = blockIdx.y;
    const int m0 = mblk * 64;
    const int mt = mblk >> 1, rowOff = (mblk & 1) * 64;
    const int t = threadIdx.x, wave = t >> 6, lane = t & 63, ln = lane & 15, qd = lane >> 4;
    const bf16_t* Ai = xb + ((size_t)mt * KB_N) * 8192 + rowOff * 64;
    const bf16_t* Bi = wimg + ((size_t)z * 8 + nblk) * KB_N * 8192;

    f32x4 acc[8];
    const f32x4 z4 = {0.f, 0.f, 0.f, 0.f};
#pragma unroll
    for (int ni = 0; ni < 8; ni++) acc[ni] = z4;

    for (int kb = 0; kb < KB_N; kb++) {
        const bf16_t* at = Ai + (size_t)kb * 8192;
        const bf16_t* bt = Bi + (size_t)kb * 8192;
#pragma unroll
        for (int i = 0; i < 2; i++)
            glds16(at + (t + i * 256) * 8, As + (t + i * 256) * 8);
#pragma unroll
        for (int i = 0; i < 4; i++)
            glds16(bt + (t + i * 256) * 8, Bs + (t + i * 256) * 8);
        __syncthreads();
#pragma unroll
        for (int kk = 0; kk < 2; kk++) {
            const int po = (((kk * 4 + qd) ^ (ln & 7)) << 3);
            s16x8 af = *(const s16x8*)(As + (wave * 16 + ln) * 64 + po);
#pragma unroll
            for (int ni = 0; ni < 8; ni++) {
                s16x8 bfr = *(const s16x8*)(Bs + (ni * 16 + ln) * 64 + po);
                acc[ni] = mfma16(af, bfr, acc[ni]);
            }
        }
        __syncthreads();
    }

    // epilogue: scatter into attention layouts
    const int b = m0 >= SP_N;            // batch uniform per block
    const int sbase = m0 - b * SP_N + wave * 16 + qd * 4;
#pragma unroll
    for (int ni = 0; ni < 8; ni++) {
        int n = nblk * 128 + ni * 16 + ln;
        float bn = bias[n];
        int h = n >> 6, d = n & 63;
        int s = sbase;
        if (s >= S_N) continue;
        if (z == 2) {
            s16x4 pk;
#pragma unroll
            for (int r = 0; r < 4; r++) pk[r] = f2bs(acc[ni][r] + bn);
            bool full = (s + 3 < S_N);
            if (!b) {
                if (full) {
                    *(s16x4*)(Vc + ((size_t)h * NT_C + (s >> 6)) * 4096 + swz(d, s & 63)) = pk;
                } else {
                    for (int r = 0; r < 4; r++)
                        if (s + r < S_N)
                            *(short*)&Vc[((size_t)h * NT_C + ((s + r) >> 6)) * 4096 + swz(d, (s + r) & 63)] = pk[r];
                }
            } else {
                if (full) {
                    *(s16x4*)(Vu + ((size_t)h * NT_U + (s >> 6)) * 4096 + swz(d, s & 63)) = pk;
                    if (s >= TEXT_N) {
                        int j = s + 1248;
                        *(s16x4*)(Vc + ((size_t)h * NT_C + (j >> 6)) * 4096 + swz(d, j & 63)) = pk;
                    } else if (s + 3 >= TEXT_N) {
                        for (int r = 0; r < 4; r++)
                            if (s + r >= TEXT_N) {
                                int j = s + r + 1248;
                                *(short*)&Vc[((size_t)h * NT_C + (j >> 6)) * 4096 + swz(d, j & 63)] = pk[r];
                            }
                    }
                } else {
                    for (int r = 0; r < 4; r++)
                        if (s + r < S_N) {
                            *(short*)&Vu[((size_t)h * NT_U + ((s + r) >> 6)) * 4096 + swz(d, (s + r) & 63)] = pk[r];
                            if (s + r >= TEXT_N) {
                                int j = s + r + 1248;
                                *(short*)&Vc[((size_t)h * NT_C + (j >> 6)) * 4096 + swz(d, j & 63)] = pk[r];
                            }
                        }
                }
            }
        } else {
#pragma unroll
            for (int r = 0; r < 4; r++) {
                int sr = s + r;
                if (sr >= S_N) continue;
                short v = f2bs(acc[ni][r] + bn);
                if (z == 0) {
                    *(short*)&Q[((size_t)(b * HEADS_N + h) * SP_N + sr) * HD_N + d] = v;
                } else {
                    if (!b) {
                        *(short*)&Kc[((size_t)h * NT_C + (sr >> 6)) * 4096 + swz(sr & 63, d)] = v;
                    } else {
                        *(short*)&Ku[((size_t)h * NT_U + (sr >> 6)) * 4096 + swz(sr & 63, d)] = v;
                        if (sr >= TEXT_N) {
                            int j = sr + 1248;
                            *(short*)&Kc[((size_t)h * NT_C + (j >> 6)) * 4096 + swz(j & 63, d)] = v;
                        }
                    }
                }
            }
        }
    }
}

// ---------------- flash attention, S^T formulation, glds double-buffer ----------------
__global__ __launch_bounds__(256) void attn_k(
    const bf16_t* __restrict__ Q, const bf16_t* __restrict__ Kc, const bf16_t* __restrict__ Ku,
    const bf16_t* __restrict__ Vc, const bf16_t* __restrict__ Vu,
    const float* __restrict__ biasc, const float* __restrict__ biasu,
    bf16_t* __restrict__ hs) {
    __shared__ __align__(16) bf16_t Ks[2][4096];   // [j][d] swizzled, dbuf
    __shared__ __align__(16) bf16_t Vs[2][4096];   // [d][j] swizzled, dbuf
    __shared__ __align__(16) bf16_t Ps[4][1024];   // per-wave P [q][j] swizzled
    __shared__ __align__(16) float  bsL[BC_N];
    const int cs = blockIdx.z, h = blockIdx.y, q0 = blockIdx.x * 64;
    const int nt = cs ? NT_U : NT_C;
    const bf16_t* Ki = cs ? (Ku + (size_t)h * NT_U * 4096) : (Kc + (size_t)h * NT_C * 4096);
    const bf16_t* Vi = cs ? (Vu + (size_t)h * NT_U * 4096) : (Vc + (size_t)h * NT_C * 4096);
    const float* bsrc = cs ? biasu : biasc;
    const int t = threadIdx.x, wave = t >> 6, lane = t & 63, ln = lane & 15, qd = lane >> 4;
    const int q = q0 + wave * 16 + ln;

    for (int i = t * 4; i < nt * 64; i += 1024)
        *(float4*)(bsL + i) = *(const float4*)(bsrc + i);

    const bf16_t* Qp = Q + ((size_t)(cs * HEADS_N + h) * SP_N + q) * HD_N;
    s16x8 qf[2];
    qf[0] = *(const s16x8*)(Qp + qd * 8);
    qf[1] = *(const s16x8*)(Qp + 32 + qd * 8);

    f32x4 o[4];
    const f32x4 z4 = {0.f, 0.f, 0.f, 0.f};
#pragma unroll
    for (int mi = 0; mi < 4; mi++) o[mi] = z4;
    f32x4 l4 = z4;                                 // vector l accumulator (deferred reduce)
    bf16_t* pw = (bf16_t*)Ps[wave];

    // prologue: stage tile 0 -> buf 0
#pragma unroll
    for (int i = 0; i < 2; i++) {
        glds16(Ki + (t + i * 256) * 8, &Ks[0][(t + i * 256) * 8]);
        glds16(Vi + (t + i * 256) * 8, &Vs[0][(t + i * 256) * 8]);
    }

    for (int kt = 0; kt < nt; kt++) {
        const int buf = kt & 1;
        __syncthreads();                               // drains prefetch from last iter
        if (kt + 1 < nt) {                             // prefetch next tile (contiguous)
            const bf16_t* kp = Ki + (size_t)(kt + 1) * 4096;
            const bf16_t* vp = Vi + (size_t)(kt + 1) * 4096;
#pragma unroll
            for (int i = 0; i < 2; i++) {
                glds16(kp + (t + i * 256) * 8, &Ks[buf ^ 1][(t + i * 256) * 8]);
                glds16(vp + (t + i * 256) * 8, &Vs[buf ^ 1][(t + i * 256) * 8]);
            }
        }

        // S^T[j][q] = sum_d K[j][d] Q[q][d]
        f32x4 st[4];
#pragma unroll
        for (int ni = 0; ni < 4; ni++) st[ni] = z4;
#pragma unroll
        for (int kk = 0; kk < 2; kk++) {
            const int po = (((kk * 4 + qd) ^ (ln & 7)) << 3);
#pragma unroll
            for (int ni = 0; ni < 4; ni++) {
                s16x8 kf = *(const s16x8*)(&Ks[buf][(ni * 16 + ln) * 64 + po]);
                st[ni] = mfma16(kf, qf[kk], st[ni]);
            }
        }
        // p = exp2(s*SCALE2 + bias-8); vector ops -> v_pk_fma/pk_add
#pragma unroll
        for (int ni = 0; ni < 4; ni++) {
            f32x4 bv4 = *(const f32x4*)(bsL + kt * 64 + ni * 16 + qd * 4);
            f32x4 s = st[ni] * SCALE2 + bv4;
            f32x4 p;
            p[0] = exp2f(s[0]); p[1] = exp2f(s[1]);
            p[2] = exp2f(s[2]); p[3] = exp2f(s[3]);
            st[ni] = p;
            l4 += p;
        }
        // pack P -> per-wave LDS (8B, swizzled)
#pragma unroll
        for (int ni = 0; ni < 4; ni++) {
            uint2 pk;
            pk.x = pk2(st[ni][0], st[ni][1]);
            pk.y = pk2(st[ni][2], st[ni][3]);
            int c0 = ni * 16 + qd * 4;
            *(uint2*)&pw[ln * 64 + ((((c0 >> 3) ^ (ln & 7)) << 3) | (c0 & 7))] = pk;
        }
        asm volatile("s_waitcnt lgkmcnt(0)" ::: "memory");  // DS-only: keeps prefetch in flight
        // O^T[d][q] += V^T P
#pragma unroll
        for (int kk = 0; kk < 2; kk++) {
            const int po = (((kk * 4 + qd) ^ (ln & 7)) << 3);
            s16x8 pb = *(const s16x8*)(&pw[ln * 64 + po]);
#pragma unroll
            for (int mi = 0; mi < 4; mi++) {
                s16x8 vf = *(const s16x8*)(&Vs[buf][(mi * 16 + ln) * 64 + po]);
                o[mi] = mfma16(vf, pb, o[mi]);
            }
        }
    }
    // deferred l reduction (pure sum, associative)
    float l_r = (l4[0] + l4[1]) + (l4[2] + l4[3]);
    l_r += __shfl_xor(l_r, 16);
    l_r += __shfl_xor(l_r, 32);
    if (q < S_N) {
        float inv = 1.f / l_r;
        int m = cs * SP_N + q;
        bf16_t* dst = hs + ((size_t)(m >> 7) * 16 + h) * 8192;
        int r = m & 127;
#pragma unroll
        for (int mi = 0; mi < 4; mi++) {
            uint2 ov;
            ov.x = pk2(o[mi][0] * inv, o[mi][1] * inv);
            ov.y = pk2(o[mi][2] * inv, o[mi][3] * inv);
            int c0 = mi * 16 + qd * 4;
            *(uint2*)&dst[r * 64 + ((((c0 >> 3) ^ (r & 7)) << 3) | (c0 & 7))] = ov;
        }
    }
}

// ---------------- output projection GEMM (64M x 128N) + split fp32 store ----------------
__global__ __launch_bounds__(256) void out_proj(
    const bf16_t* __restrict__ hsi, const bf16_t* __restrict__ wimg,
    const float* __restrict__ bo, float* __restrict__ out) {
    __shared__ __align__(16) bf16_t As[4096];    // 64 x 64
    __shared__ __align__(16) bf16_t Bs[8192];    // 128 x 64
    const int nblk = blockIdx.x, mblk = blockIdx.y;
    const int m0 = mblk * 64;
    const int mt = mblk >> 1, rowOff = (mblk & 1) * 64;
    const int t = threadIdx.x, wave = t >> 6, lane = t & 63, ln = lane & 15, qd = lane >> 4;
    const bf16_t* Ai = hsi + ((size_t)mt * KB_N) * 8192 + rowOff * 64;
    const bf16_t* Bi = wimg + ((size_t)3 * 8 + nblk) * KB_N * 8192;

    f32x4 acc[8];
    const f32x4 z4 = {0.f, 0.f, 0.f, 0.f};
#pragma unroll
    for (int ni = 0; ni < 8; ni++) acc[ni] = z4;

    for (int kb = 0; kb < KB_N; kb++) {
        const bf16_t* at = Ai + (size_t)kb * 8192;
        const bf16_t* bt = Bi + (size_t)kb * 8192;
#pragma unroll
        for (int i = 0; i < 2; i++)
            glds16(at + (t + i * 256) * 8, As + (t + i * 256) * 8);
#pragma unroll
        for (int i = 0; i < 4; i++)
            glds16(bt + (t + i * 256) * 8, Bs + (t + i * 256) * 8);
        __syncthreads();
#pragma unroll
        for (int kk = 0; kk < 2; kk++) {
            const int po = (((kk * 4 + qd) ^ (ln & 7)) << 3);
            s16x8 af = *(const s16x8*)(As + (wave * 16 + ln) * 64 + po);
#pragma unroll
            for (int ni = 0; ni < 8; ni++) {
                s16x8 bfr = *(const s16x8*)(Bs + (ni * 16 + ln) * 64 + po);
                acc[ni] = mfma16(af, bfr, acc[ni]);
            }
        }
        __syncthreads();
    }
    const int b = m0 >= SP_N;
    const int sbase = m0 - b * SP_N + wave * 16 + qd * 4;
#pragma unroll
    for (int ni = 0; ni < 8; ni++) {
        int n = nblk * 128 + ni * 16 + ln;
        float bn = bo[n];
#pragma unroll
        for (int r = 0; r < 4; r++) {
            int s = sbase + r;
            if (s >= S_N) continue;
            float v = acc[ni][r] + bn;
            size_t off = (s >= TEXT_N)
                ? ((size_t)(b * ST_N + (s - TEXT_N)) * D_N + n)
                : ((size_t)2 * ST_N * D_N + (size_t)(b * TEXT_N + s) * D_N + n);
            out[off] = v;
        }
    }
}

extern "C" void kernel_launch(void* const* d_in, const int* in_sizes, int n_in,
                              void* d_out, int out_size, void* d_ws, size_t ws_size,
                              hipStream_t stream) {
    const float* hid = (const float*)d_in[0];
    const float* enc = (const float*)d_in[1];
    const int*  mask = (const int*)d_in[2];
    const float* wq = (const float*)d_in[3];
    const float* bq = (const float*)d_in[4];
    const float* wk = (const float*)d_in[5];
    const float* bk = (const float*)d_in[6];
    const float* wv = (const float*)d_in[7];
    const float* bv = (const float*)d_in[8];
    const float* wo = (const float*)d_in[9];
    const float* bo = (const float*)d_in[10];

    bf16_t* w = (bf16_t*)d_ws;
    const size_t WIMG = (size_t)4 * 8 * 16 * 8192;        // 4,194,304
    const size_t XIMG = (size_t)MB_N * KB_N * 8192;       // 3,145,728
    bf16_t* wimg = w;
    bf16_t* xb   = wimg + WIMG;
    bf16_t* Qb   = xb + XIMG;                             // [2][16][1536][64]
    bf16_t* Kc   = Qb + (size_t)2 * HEADS_N * SP_N * HD_N;// [16][43][4096]
    bf16_t* Ku   = Kc + (size_t)HEADS_N * NT_C * 4096;    // [16][24][4096]
    bf16_t* Vc   = Ku + (size_t)HEADS_N * NT_U * 4096;    // [16][43][4096]
    bf16_t* Vu   = Vc + (size_t)HEADS_N * NT_C * 4096;    // [16][24][4096]
    float*  biasc = (float*)(Vu + (size_t)HEADS_N * NT_U * 4096);
    float*  biasu = biasc + BC_N;
    bf16_t* hsi  = xb;   // reuse x-image region for hs image (xb dead after qkv_proj)

    prep<<<913, 256, 0, stream>>>(hid, enc, mask, wq, wk, wv, wo, wimg, xb, biasc, biasu);
    qkv_proj<<<dim3(8, 48, 3), 256, 0, stream>>>(xb, wimg, bq, bk, bv, Qb, Kc, Ku, Vc, Vu);
    attn_k<<<dim3(24, 16, 2), 256, 0, stream>>>(Qb, Kc, Ku, Vc, Vu, biasc, biasu, hsi);
    out_proj<<<dim3(8, 48), 256, 0, stream>>>(hsi, wimg, bo, (float*)d_out);
}

// Round 13
// 191.241 us; speedup vs baseline: 1.1799x; 1.0611x over previous
//
#include <hip/hip_runtime.h>
#include <hip/hip_bf16.h>
#include <hip/hip_fp16.h>

#define TEXT_N 226
#define D_N    1024
#define HEADS_N 16
#define HD_N   64
#define ST_N   1248
#define S_N    1474        // TEXT+ST
#define L0_N   2722        // S+ST (cond key length)
#define NT_C   43          // cond j-tiles (64 each) -> 2752
#define NT_U   24          // uncond j-tiles        -> 1536
#define BC_N   (NT_C*64)   // 2752 cond bias entries
#define SP_N   1536        // padded per-batch rows
#define MB_N   24          // 128-row image blocks (3072 rows)
#define KB_N   16          // k-blocks of 64 (K=1024)
#define NEGB2  (-1.442695e9f)            // -1e9 * log2(e)
#define SCALE2 (0.125f * 1.44269504f)    // (1/sqrt(64)) * log2(e)

typedef __hip_bfloat16 bf16_t;
typedef short s16x8 __attribute__((ext_vector_type(8)));   // 8 bf16 (4 VGPRs)
typedef short s16x4 __attribute__((ext_vector_type(4)));   // 4 bf16
typedef float f32x4 __attribute__((ext_vector_type(4)));

__device__ __forceinline__ f32x4 mfma16(s16x8 a, s16x8 b, f32x4 c) {
    return __builtin_amdgcn_mfma_f32_16x16x32_bf16(a, b, c, 0, 0, 0);
}

typedef __attribute__((address_space(1))) const unsigned int gu32;
typedef __attribute__((address_space(3))) unsigned int lu32;
__device__ __forceinline__ void glds16(const void* g, void* l) {
    __builtin_amdgcn_global_load_lds((gu32*)g, (lu32*)l, 16, 0, 0);
}

// finite-only RNE f32->bf16 (matches __float2bfloat16 for finite values)
__device__ __forceinline__ short f2bs(float x) {
    unsigned u = __float_as_uint(x);
    u += 0x7FFF + ((u >> 16) & 1);
    return (short)(u >> 16);
}
// swizzled elem offset inside a [R][64] bf16 tile: 16B unit XORed by (row&7)
__device__ __forceinline__ int swz(int r, int c) {
    return r * 64 + ((((c >> 3) ^ (r & 7)) << 3) | (c & 7));
}

// ---------------- prep: weight images, x image, bias vectors ----------------
__global__ __launch_bounds__(256) void prep(
    const float* __restrict__ hid, const float* __restrict__ enc,
    const int* __restrict__ mask,
    const float* __restrict__ wq, const float* __restrict__ wk,
    const float* __restrict__ wv, const float* __restrict__ wo,
    bf16_t* __restrict__ wimg, bf16_t* __restrict__ xb,
    float* __restrict__ biasc, float* __restrict__ biasu) {
    __shared__ float Lw[64 * 129];
    const int b = blockIdx.x, t = threadIdx.x;
    if (b < 512) {                       // 4 weights x 8 nblk x 16 kb
        const int wid = b >> 7, nblk = (b >> 4) & 7, kb = b & 15;
        const float* w = (wid == 0) ? wq : (wid == 1) ? wk : (wid == 2) ? wv : wo;
        const int k0 = kb * 64, n0 = nblk * 128;
#pragma unroll
        for (int i = 0; i < 8; i++) {
            int idx = t + i * 256;
            int kr = idx >> 5, c4 = (idx & 31) * 4;
            float4 v = *(const float4*)(w + (size_t)(k0 + kr) * D_N + n0 + c4);
            Lw[kr * 129 + c4 + 0] = v.x; Lw[kr * 129 + c4 + 1] = v.y;
            Lw[kr * 129 + c4 + 2] = v.z; Lw[kr * 129 + c4 + 3] = v.w;
        }
        __syncthreads();
        bf16_t* dst = wimg + (((size_t)wid * 8 + nblk) * 16 + kb) * 8192;
#pragma unroll
        for (int i = 0; i < 4; i++) {
            int u = t + i * 256;
            int r = u >> 3, p = u & 7;
            int ul = p ^ (r & 7);
            s16x8 o;
#pragma unroll
            for (int e = 0; e < 8; e++)
                o[e] = f2bs(Lw[(ul * 8 + e) * 129 + r]);
            *(s16x8*)(dst + r * 64 + p * 8) = o;
        }
    } else if (b < 896) {                // 384 x-tiles
        const int tile = b - 512;
        const int mblk = tile >> 4, kb = tile & 15;
        bf16_t* dst = xb + (size_t)tile * 8192;
#pragma unroll
        for (int i = 0; i < 4; i++) {
            int u = t + i * 256;
            int r = u >> 3, p = u & 7;
            int m = mblk * 128 + r;
            int bb = m >= SP_N; int s = m - bb * SP_N;
            if (s >= S_N) continue;
            const float* src = (s < TEXT_N)
                ? (enc + (size_t)(bb * TEXT_N + s) * D_N)
                : (hid + (size_t)(bb * ST_N + (s - TEXT_N)) * D_N);
            int k = kb * 64 + (p ^ (r & 7)) * 8;
            float4 f0 = *(const float4*)(src + k);
            float4 f1 = *(const float4*)(src + k + 4);
            s16x8 o;
            o[0]=f2bs(f0.x); o[1]=f2bs(f0.y); o[2]=f2bs(f0.z); o[3]=f2bs(f0.w);
            o[4]=f2bs(f1.x); o[5]=f2bs(f1.y); o[6]=f2bs(f1.z); o[7]=f2bs(f1.w);
            *(s16x8*)(dst + r * 64 + p * 8) = o;
        }
    } else {                             // bias vectors (exp2 domain, -8 max-shift folded in)
        int j = (b - 896) * 256 + t;
        if (j < BC_N) {
            float v = -8.f;
            if (j >= L0_N) v = NEGB2;
            else if (j >= S_N) v = (mask[j - S_N] > 0) ? -8.f : NEGB2;
            biasc[j] = v;
        }
        int j2 = j - BC_N;
        if (j2 >= 0 && j2 < SP_N) biasu[j2] = (j2 < S_N) ? -8.f : NEGB2;
    }
}

// ---------------- fused QKV projection GEMM (64M x 128N, glds staging) ----------------
__global__ __launch_bounds__(256) void qkv_proj(
    const bf16_t* __restrict__ xb, const bf16_t* __restrict__ wimg,
    const float* __restrict__ bq, const float* __restrict__ bk, const float* __restrict__ bv,
    bf16_t* __restrict__ Q, bf16_t* __restrict__ Kc, bf16_t* __restrict__ Ku,
    bf16_t* __restrict__ Vc, bf16_t* __restrict__ Vu) {
    __shared__ __align__(16) bf16_t As[4096];    // 64 x 64
    __shared__ __align__(16) bf16_t Bs[8192];    // 128 x 64
    const int z = blockIdx.z;
    const float* bias = (z == 0) ? bq : (z == 1) ? bk : bv;
    const int nblk = blockIdx.x, mblk = blockIdx.y;
    const int m0 = mblk * 64;
    const int mt = mblk >> 1, rowOff = (mblk & 1) * 64;
    const int t = threadIdx.x, wave = t >> 6, lane = t & 63, ln = lane & 15, qd = lane >> 4;
    const bf16_t* Ai = xb + ((size_t)mt * KB_N) * 8192 + rowOff * 64;
    const bf16_t* Bi = wimg + ((size_t)z * 8 + nblk) * KB_N * 8192;

    f32x4 acc[8];
    const f32x4 z4 = {0.f, 0.f, 0.f, 0.f};
#pragma unroll
    for (int ni = 0; ni < 8; ni++) acc[ni] = z4;

    for (int kb = 0; kb < KB_N; kb++) {
        const bf16_t* at = Ai + (size_t)kb * 8192;
        const bf16_t* bt = Bi + (size_t)kb * 8192;
#pragma unroll
        for (int i = 0; i < 2; i++)
            glds16(at + (t + i * 256) * 8, As + (t + i * 256) * 8);
#pragma unroll
        for (int i = 0; i < 4; i++)
            glds16(bt + (t + i * 256) * 8, Bs + (t + i * 256) * 8);
        __syncthreads();
#pragma unroll
        for (int kk = 0; kk < 2; kk++) {
            const int po = (((kk * 4 + qd) ^ (ln & 7)) << 3);
            s16x8 af = *(const s16x8*)(As + (wave * 16 + ln) * 64 + po);
#pragma unroll
            for (int ni = 0; ni < 8; ni++) {
                s16x8 bfr = *(const s16x8*)(Bs + (ni * 16 + ln) * 64 + po);
                acc[ni] = mfma16(af, bfr, acc[ni]);
            }
        }
        __syncthreads();
    }

    // epilogue: scatter into attention layouts
    const int b = m0 >= SP_N;            // batch uniform per block
    const int sbase = m0 - b * SP_N + wave * 16 + qd * 4;
#pragma unroll
    for (int ni = 0; ni < 8; ni++) {
        int n = nblk * 128 + ni * 16 + ln;
        float bn = bias[n];
        int h = n >> 6, d = n & 63;
        int s = sbase;
        if (s >= S_N) continue;
        if (z == 2) {
            s16x4 pk;
#pragma unroll
            for (int r = 0; r < 4; r++) pk[r] = f2bs(acc[ni][r] + bn);
            bool full = (s + 3 < S_N);
            if (!b) {
                if (full) {
                    *(s16x4*)(Vc + ((size_t)h * NT_C + (s >> 6)) * 4096 + swz(d, s & 63)) = pk;
                } else {
                    for (int r = 0; r < 4; r++)
                        if (s + r < S_N)
                            *(short*)&Vc[((size_t)h * NT_C + ((s + r) >> 6)) * 4096 + swz(d, (s + r) & 63)] = pk[r];
                }
            } else {
                if (full) {
                    *(s16x4*)(Vu + ((size_t)h * NT_U + (s >> 6)) * 4096 + swz(d, s & 63)) = pk;
                    if (s >= TEXT_N) {
                        int j = s + 1248;
                        *(s16x4*)(Vc + ((size_t)h * NT_C + (j >> 6)) * 4096 + swz(d, j & 63)) = pk;
                    } else if (s + 3 >= TEXT_N) {
                        for (int r = 0; r < 4; r++)
                            if (s + r >= TEXT_N) {
                                int j = s + r + 1248;
                                *(short*)&Vc[((size_t)h * NT_C + (j >> 6)) * 4096 + swz(d, j & 63)] = pk[r];
                            }
                    }
                } else {
                    for (int r = 0; r < 4; r++)
                        if (s + r < S_N) {
                            *(short*)&Vu[((size_t)h * NT_U + ((s + r) >> 6)) * 4096 + swz(d, (s + r) & 63)] = pk[r];
                            if (s + r >= TEXT_N) {
                                int j = s + r + 1248;
                                *(short*)&Vc[((size_t)h * NT_C + (j >> 6)) * 4096 + swz(d, j & 63)] = pk[r];
                            }
                        }
                }
            }
        } else {
#pragma unroll
            for (int r = 0; r < 4; r++) {
                int sr = s + r;
                if (sr >= S_N) continue;
                short v = f2bs(acc[ni][r] + bn);
                if (z == 0) {
                    *(short*)&Q[((size_t)(b * HEADS_N + h) * SP_N + sr) * HD_N + d] = v;
                } else {
                    if (!b) {
                        *(short*)&Kc[((size_t)h * NT_C + (sr >> 6)) * 4096 + swz(sr & 63, d)] = v;
                    } else {
                        *(short*)&Ku[((size_t)h * NT_U + (sr >> 6)) * 4096 + swz(sr & 63, d)] = v;
                        if (sr >= TEXT_N) {
                            int j = sr + 1248;
                            *(short*)&Kc[((size_t)h * NT_C + (j >> 6)) * 4096 + swz(j & 63, d)] = v;
                        }
                    }
                }
            }
        }
    }
}

// ---------------- flash attention, split-K, single-buffer, lean LDS ----------------
// grid (24 qt, 16 h, 4 z): z = cs*2 + sp. Partials additive (no online max since R8).
__global__ __launch_bounds__(256, 6) void attn_k(
    const bf16_t* __restrict__ Q, const bf16_t* __restrict__ Kc, const bf16_t* __restrict__ Ku,
    const bf16_t* __restrict__ Vc, const bf16_t* __restrict__ Vu,
    const float* __restrict__ biasc, const float* __restrict__ biasu,
    __half* __restrict__ Opart, float* __restrict__ Lpart) {
    __shared__ __align__(16) bf16_t Ks[4096];      // [j][d] swizzled
    __shared__ __align__(16) bf16_t Vs[4096];      // [d][j] swizzled
    __shared__ __align__(16) bf16_t Ps[4][1024];   // per-wave P [q][j] swizzled
    const int qt = blockIdx.x, h = blockIdx.y, z = blockIdx.z;
    const int cs = z >> 1, sp = z & 1;
    const int q0 = qt * 64;
    const int nt = cs ? NT_U : NT_C;
    const int half = (nt + 1) >> 1;                // 22 / 12
    const int kt0 = sp ? half : 0;
    const int kt1 = sp ? nt : half;
    const bf16_t* Ki = cs ? (Ku + (size_t)h * NT_U * 4096) : (Kc + (size_t)h * NT_C * 4096);
    const bf16_t* Vi = cs ? (Vu + (size_t)h * NT_U * 4096) : (Vc + (size_t)h * NT_C * 4096);
    const float* bsrc = cs ? biasu : biasc;
    const int t = threadIdx.x, wave = t >> 6, lane = t & 63, ln = lane & 15, qd = lane >> 4;
    const int q = q0 + wave * 16 + ln;

    const bf16_t* Qp = Q + ((size_t)(cs * HEADS_N + h) * SP_N + q) * HD_N;
    s16x8 qf[2];
    qf[0] = *(const s16x8*)(Qp + qd * 8);
    qf[1] = *(const s16x8*)(Qp + 32 + qd * 8);

    f32x4 o[4];
    const f32x4 z4 = {0.f, 0.f, 0.f, 0.f};
#pragma unroll
    for (int mi = 0; mi < 4; mi++) o[mi] = z4;
    f32x4 l4 = z4;
    bf16_t* pw = (bf16_t*)Ps[wave];

    for (int kt = kt0; kt < kt1; kt++) {
        const bf16_t* kp = Ki + (size_t)kt * 4096;
        const bf16_t* vp = Vi + (size_t)kt * 4096;
#pragma unroll
        for (int i = 0; i < 2; i++) {
            glds16(kp + (t + i * 256) * 8, Ks + (t + i * 256) * 8);
            glds16(vp + (t + i * 256) * 8, Vs + (t + i * 256) * 8);
        }
        __syncthreads();

        // bias regs (only tiles >= 23 have non-constant bias; issued before MFMA)
        f32x4 bv[4];
        if (kt >= 23) {
#pragma unroll
            for (int ni = 0; ni < 4; ni++)
                bv[ni] = *(const f32x4*)(bsrc + kt * 64 + ni * 16 + qd * 4);
        } else {
            const f32x4 m8 = {-8.f, -8.f, -8.f, -8.f};
#pragma unroll
            for (int ni = 0; ni < 4; ni++) bv[ni] = m8;
        }

        // S^T[j][q] = sum_d K[j][d] Q[q][d]
        f32x4 st[4];
#pragma unroll
        for (int ni = 0; ni < 4; ni++) st[ni] = z4;
#pragma unroll
        for (int kk = 0; kk < 2; kk++) {
            const int po = (((kk * 4 + qd) ^ (ln & 7)) << 3);
#pragma unroll
            for (int ni = 0; ni < 4; ni++) {
                s16x8 kf = *(const s16x8*)(Ks + (ni * 16 + ln) * 64 + po);
                st[ni] = mfma16(kf, qf[kk], st[ni]);
            }
        }
        // p = exp2(s*SCALE2 + bias-8); vector ops
#pragma unroll
        for (int ni = 0; ni < 4; ni++) {
            f32x4 s = st[ni] * SCALE2 + bv[ni];
            f32x4 p;
            p[0] = exp2f(s[0]); p[1] = exp2f(s[1]);
            p[2] = exp2f(s[2]); p[3] = exp2f(s[3]);
            st[ni] = p;
            l4 += p;
        }
        // pack P -> per-wave LDS (8B, swizzled)
#pragma unroll
        for (int ni = 0; ni < 4; ni++) {
            uint2 pk;
            {
                float2 f; f.x = st[ni][0]; f.y = st[ni][1];
                __hip_bfloat162 hh = __float22bfloat162_rn(f);
                pk.x = *(unsigned*)&hh;
                f.x = st[ni][2]; f.y = st[ni][3];
                hh = __float22bfloat162_rn(f);
                pk.y = *(unsigned*)&hh;
            }
            int c0 = ni * 16 + qd * 4;
            *(uint2*)&pw[ln * 64 + ((((c0 >> 3) ^ (ln & 7)) << 3) | (c0 & 7))] = pk;
        }
        asm volatile("s_waitcnt lgkmcnt(0)" ::: "memory");
        // O^T[d][q] += V^T P
#pragma unroll
        for (int kk = 0; kk < 2; kk++) {
            const int po = (((kk * 4 + qd) ^ (ln & 7)) << 3);
            s16x8 pb = *(const s16x8*)(&pw[ln * 64 + po]);
#pragma unroll
            for (int mi = 0; mi < 4; mi++) {
                s16x8 vf = *(const s16x8*)(&Vs[(mi * 16 + ln) * 64 + po]);
                o[mi] = mfma16(vf, pb, o[mi]);
            }
        }
        __syncthreads();
    }

    // store fp16 partial O (unnormalized) layout [q][d] (q = wave*16+ln!), fp32 partial l
    const int tix = ((cs * 16 + h) * 24 + qt) * 2 + sp;
    __half* op = Opart + (size_t)tix * 4096;
#pragma unroll
    for (int mi = 0; mi < 4; mi++) {
        int c0 = mi * 16 + qd * 4;
        float2 f0; f0.x = o[mi][0]; f0.y = o[mi][1];
        float2 f1; f1.x = o[mi][2]; f1.y = o[mi][3];
        __half2 h0 = __float22half2_rn(f0);
        __half2 h1 = __float22half2_rn(f1);
        uint2 u; u.x = *(unsigned*)&h0; u.y = *(unsigned*)&h1;
        *(uint2*)(op + (wave * 16 + ln) * 64 + c0) = u;
    }
    float l_r = (l4[0] + l4[1]) + (l4[2] + l4[3]);
    l_r += __shfl_xor(l_r, 16);
    l_r += __shfl_xor(l_r, 32);
    if (qd == 0) Lpart[(size_t)tix * 64 + wave * 16 + ln] = l_r;
}

// ---------------- split-K reduce: sum partials, normalize, write hs image ----------------
__global__ __launch_bounds__(256) void attn_red(
    const __half* __restrict__ Opart, const float* __restrict__ Lpart,
    bf16_t* __restrict__ hs) {
    __shared__ float linv[64];
    const int qt = blockIdx.x, h = blockIdx.y, cs = blockIdx.z;
    const int base = ((cs * 16 + h) * 24 + qt) * 2;
    const __half* p0 = Opart + (size_t)base * 4096;
    const __half* p1 = p0 + 4096;
    const int t = threadIdx.x;
    if (t < 64) linv[t] = 1.f / (Lpart[(size_t)base * 64 + t] + Lpart[(size_t)(base + 1) * 64 + t]);
    __syncthreads();
    const int q = t >> 2, c0 = (t & 3) * 16;
    const int m = cs * SP_N + qt * 64 + q;
    const float inv = linv[q];
    bf16_t* dst = hs + ((size_t)(m >> 7) * 16 + h) * 8192;
    const int r = m & 127;
#pragma unroll
    for (int hh = 0; hh < 2; hh++) {
        int c = c0 + hh * 8;
        const __half2* a2 = (const __half2*)(p0 + q * 64 + c);
        const __half2* b2 = (const __half2*)(p1 + q * 64 + c);
        s16x8 o8;
#pragma unroll
        for (int e = 0; e < 4; e++) {
            float2 fa = __half22float2(a2[e]);
            float2 fb = __half22float2(b2[e]);
            o8[2 * e]     = f2bs((fa.x + fb.x) * inv);
            o8[2 * e + 1] = f2bs((fa.y + fb.y) * inv);
        }
        *(s16x8*)(dst + r * 64 + (((c >> 3) ^ (r & 7)) << 3)) = o8;
    }
}

// ---------------- output projection GEMM (64M x 128N) + split fp32 store ----------------
__global__ __launch_bounds__(256) void out_proj(
    const bf16_t* __restrict__ hsi, const bf16_t* __restrict__ wimg,
    const float* __restrict__ bo, float* __restrict__ out) {
    __shared__ __align__(16) bf16_t As[4096];    // 64 x 64
    __shared__ __align__(16) bf16_t Bs[8192];    // 128 x 64
    const int nblk = blockIdx.x, mblk = blockIdx.y;
    const int m0 = mblk * 64;
    const int mt = mblk >> 1, rowOff = (mblk & 1) * 64;
    const int t = threadIdx.x, wave = t >> 6, lane = t & 63, ln = lane & 15, qd = lane >> 4;
    const bf16_t* Ai = hsi + ((size_t)mt * KB_N) * 8192 + rowOff * 64;
    const bf16_t* Bi = wimg + ((size_t)3 * 8 + nblk) * KB_N * 8192;

    f32x4 acc[8];
    const f32x4 z4 = {0.f, 0.f, 0.f, 0.f};
#pragma unroll
    for (int ni = 0; ni < 8; ni++) acc[ni] = z4;

    for (int kb = 0; kb < KB_N; kb++) {
        const bf16_t* at = Ai + (size_t)kb * 8192;
        const bf16_t* bt = Bi + (size_t)kb * 8192;
#pragma unroll
        for (int i = 0; i < 2; i++)
            glds16(at + (t + i * 256) * 8, As + (t + i * 256) * 8);
#pragma unroll
        for (int i = 0; i < 4; i++)
            glds16(bt + (t + i * 256) * 8, Bs + (t + i * 256) * 8);
        __syncthreads();
#pragma unroll
        for (int kk = 0; kk < 2; kk++) {
            const int po = (((kk * 4 + qd) ^ (ln & 7)) << 3);
            s16x8 af = *(const s16x8*)(As + (wave * 16 + ln) * 64 + po);
#pragma unroll
            for (int ni = 0; ni < 8; ni++) {
                s16x8 bfr = *(const s16x8*)(Bs + (ni * 16 + ln) * 64 + po);
                acc[ni] = mfma16(af, bfr, acc[ni]);
            }
        }
        __syncthreads();
    }
    const int b = m0 >= SP_N;
    const int sbase = m0 - b * SP_N + wave * 16 + qd * 4;
#pragma unroll
    for (int ni = 0; ni < 8; ni++) {
        int n = nblk * 128 + ni * 16 + ln;
        float bn = bo[n];
#pragma unroll
        for (int r = 0; r < 4; r++) {
            int s = sbase + r;
            if (s >= S_N) continue;
            float v = acc[ni][r] + bn;
            size_t off = (s >= TEXT_N)
                ? ((size_t)(b * ST_N + (s - TEXT_N)) * D_N + n)
                : ((size_t)2 * ST_N * D_N + (size_t)(b * TEXT_N + s) * D_N + n);
            out[off] = v;
        }
    }
}

extern "C" void kernel_launch(void* const* d_in, const int* in_sizes, int n_in,
                              void* d_out, int out_size, void* d_ws, size_t ws_size,
                              hipStream_t stream) {
    const float* hid = (const float*)d_in[0];
    const float* enc = (const float*)d_in[1];
    const int*  mask = (const int*)d_in[2];
    const float* wq = (const float*)d_in[3];
    const float* bq = (const float*)d_in[4];
    const float* wk = (const float*)d_in[5];
    const float* bk = (const float*)d_in[6];
    const float* wv = (const float*)d_in[7];
    const float* bv = (const float*)d_in[8];
    const float* wo = (const float*)d_in[9];
    const float* bo = (const float*)d_in[10];

    bf16_t* w = (bf16_t*)d_ws;
    const size_t WIMG = (size_t)4 * 8 * 16 * 8192;        // 4,194,304
    const size_t XIMG = (size_t)MB_N * KB_N * 8192;       // 3,145,728
    bf16_t* wimg = w;
    bf16_t* xb   = wimg + WIMG;
    bf16_t* Qb   = xb + XIMG;                             // [2][16][1536][64]
    bf16_t* Kc   = Qb + (size_t)2 * HEADS_N * SP_N * HD_N;// [16][43][4096]
    bf16_t* Ku   = Kc + (size_t)HEADS_N * NT_C * 4096;    // [16][24][4096]
    bf16_t* Vc   = Ku + (size_t)HEADS_N * NT_U * 4096;    // [16][43][4096]
    bf16_t* Vu   = Vc + (size_t)HEADS_N * NT_C * 4096;    // [16][24][4096]
    float*  biasc = (float*)(Vu + (size_t)HEADS_N * NT_U * 4096);
    float*  biasu = biasc + BC_N;
    __half* Opart = (__half*)(biasu + SP_N);              // [1536 tiles][4096] fp16
    float*  Lpart = (float*)(Opart + (size_t)1536 * 4096);// [1536][64] fp32
    bf16_t* hsi  = xb;   // reuse x-image region for hs image (xb dead after qkv_proj)

    prep<<<913, 256, 0, stream>>>(hid, enc, mask, wq, wk, wv, wo, wimg, xb, biasc, biasu);
    qkv_proj<<<dim3(8, 48, 3), 256, 0, stream>>>(xb, wimg, bq, bk, bv, Qb, Kc, Ku, Vc, Vu);
    attn_k<<<dim3(24, 16, 4), 256, 0, stream>>>(Qb, Kc, Ku, Vc, Vu, biasc, biasu, Opart, Lpart);
    attn_red<<<dim3(24, 16, 2), 256, 0, stream>>>(Opart, Lpart, hsi);
    out_proj<<<dim3(8, 48), 256, 0, stream>>>(hsi, wimg, bo, (float*)d_out);
}